// Round 3
// baseline (215.048 us; speedup 1.0000x reference)
//
#include <hip/hip_runtime.h>
#include <stdint.h>

// SortNode2Pin: per-node argmin over CSR pin slices by sorted_pin_map key.
// Strategy: 4-bit coarse-key table (4 MB, per-XCD-L2-resident) for the random
// gather; exact key gathers only on coarse-min ties. NT loads for streaming
// data to preserve L2 residency of the coarse table.

typedef int iv4 __attribute__((ext_vector_type(4)));

__global__ void build_key4_kernel(const int* __restrict__ key,
                                  uint32_t* __restrict__ key4,
                                  int num_pins, int shift) {
    int t = blockIdx.x * blockDim.x + threadIdx.x;
    int base = t * 8;
    if (base >= num_pins) return;
    if (base + 8 <= num_pins) {
        const iv4* kp = (const iv4*)(key + base);
        iv4 a = __builtin_nontemporal_load(kp);
        iv4 b = __builtin_nontemporal_load(kp + 1);
        uint32_t w = 0;
        w |= (((uint32_t)a.x >> shift) & 15u) << 0;
        w |= (((uint32_t)a.y >> shift) & 15u) << 4;
        w |= (((uint32_t)a.z >> shift) & 15u) << 8;
        w |= (((uint32_t)a.w >> shift) & 15u) << 12;
        w |= (((uint32_t)b.x >> shift) & 15u) << 16;
        w |= (((uint32_t)b.y >> shift) & 15u) << 20;
        w |= (((uint32_t)b.z >> shift) & 15u) << 24;
        w |= (((uint32_t)b.w >> shift) & 15u) << 28;
        key4[t] = w;
    } else {
        uint32_t w = 0;
        for (int j = 0; base + j < num_pins; ++j) {
            uint32_t k = (uint32_t)key[base + j];
            w |= ((k >> shift) & 15u) << (4 * j);
        }
        key4[t] = w;
    }
}

__global__ void SortNode2Pin_coarse_kernel(const int* __restrict__ starts,
                                           const int* __restrict__ n2p,
                                           const int* __restrict__ key,
                                           const uint32_t* __restrict__ key4,
                                           int* __restrict__ out,
                                           int num_nodes) {
    int i = blockIdx.x * blockDim.x + threadIdx.x;
    if (i >= num_nodes) return;
    int s = __builtin_nontemporal_load(starts + i);
    int e = __builtin_nontemporal_load(starts + i + 1);

    // Pass 1: coarse argmin on 4-bit keys (key4 gather is L2-resident).
    int mv = 16;     // min nibble seen
    int cnt = 0;     // how many pins attain mv
    int fp = 0;      // first pin attaining mv (answer if cnt==1; 0 if empty)
    for (int j = s; j < e; ++j) {
        int p = __builtin_nontemporal_load(n2p + j);
        uint32_t w = key4[(uint32_t)p >> 3];
        int n = (int)((w >> (((uint32_t)p & 7u) * 4u)) & 15u);
        if (n < mv) { mv = n; cnt = 1; fp = p; }
        else if (n == mv) { ++cnt; }
    }

    int result;
    if (cnt <= 1) {
        result = fp;   // unique coarse min (or empty node -> 0)
    } else {
        // Pass 2: exact resolution among coarse-min candidates only.
        int bk = 0x7fffffff, bp = 0;
        for (int j = s; j < e; ++j) {
            int p = __builtin_nontemporal_load(n2p + j);
            uint32_t w = key4[(uint32_t)p >> 3];
            int n = (int)((w >> (((uint32_t)p & 7u) * 4u)) & 15u);
            if (n == mv) {
                int k = __builtin_nontemporal_load(key + p);
                if (k < bk) { bk = k; bp = p; }
            }
        }
        result = bp;
    }
    __builtin_nontemporal_store(result, out + i);
}

// Fallback (round-1 kernel) if workspace is too small for the coarse table.
__global__ void SortNode2Pin_direct_kernel(const int* __restrict__ starts,
                                           const int* __restrict__ n2p,
                                           const int* __restrict__ key,
                                           int* __restrict__ out,
                                           int num_nodes) {
    int i = blockIdx.x * blockDim.x + threadIdx.x;
    if (i >= num_nodes) return;
    int s = starts[i];
    int e = starts[i + 1];
    int best_pin = 0;
    int best_key = 0x7fffffff;
    for (int j = s; j < e; ++j) {
        int p = n2p[j];
        int k = key[p];
        if (k < best_key) { best_key = k; best_pin = p; }
    }
    out[i] = best_pin;
}

extern "C" void kernel_launch(void* const* d_in, const int* in_sizes, int n_in,
                              void* d_out, int out_size, void* d_ws, size_t ws_size,
                              hipStream_t stream) {
    const int* starts = (const int*)d_in[0];   // [num_nodes+1]
    const int* n2p    = (const int*)d_in[1];   // [num_pins]
    const int* key    = (const int*)d_in[2];   // [num_pins]
    int num_nodes = out_size;
    int num_pins  = in_sizes[1];

    size_t key4_words = (size_t)((num_pins + 7) / 8);
    size_t need = key4_words * sizeof(uint32_t);

    int block = 256;
    if (ws_size >= need) {
        // shift so coarse key = top 4 bits of key range [0, num_pins)
        int bits = 32 - __builtin_clz((unsigned)(num_pins - 1));  // ceil(log2)
        int shift = bits > 4 ? bits - 4 : 0;
        uint32_t* key4 = (uint32_t*)d_ws;

        int g1 = (int)((key4_words + block - 1) / block);
        build_key4_kernel<<<g1, block, 0, stream>>>(key, key4, num_pins, shift);

        int g2 = (num_nodes + block - 1) / block;
        SortNode2Pin_coarse_kernel<<<g2, block, 0, stream>>>(
            starts, n2p, key, key4, (int*)d_out, num_nodes);
    } else {
        int grid = (num_nodes + block - 1) / block;
        SortNode2Pin_direct_kernel<<<grid, block, 0, stream>>>(
            starts, n2p, key, (int*)d_out, num_nodes);
    }
}

// Round 4
// 119.626 us; speedup vs baseline: 1.7977x; 1.7977x over previous
//
#include <hip/hip_runtime.h>
#include <stdint.h>

// SortNode2Pin: per-node argmin over CSR pin slices by sorted_pin_map key.
// 4-bit coarse-key table (4 MB, L2-resident) serves the random gather;
// exact key[] gathers happen lazily, only for pins that TIE the running
// minimum nibble (expected <1 per node). Single pass, no re-loop.

typedef int iv4 __attribute__((ext_vector_type(4)));

__global__ void build_key4_kernel(const int* __restrict__ key,
                                  uint32_t* __restrict__ key4,
                                  int num_pins, int shift) {
    int t = blockIdx.x * blockDim.x + threadIdx.x;
    int base = t * 8;
    if (base >= num_pins) return;
    if (base + 8 <= num_pins) {
        const iv4* kp = (const iv4*)(key + base);
        iv4 a = __builtin_nontemporal_load(kp);
        iv4 b = __builtin_nontemporal_load(kp + 1);
        uint32_t w = 0;
        w |= (((uint32_t)a.x >> shift) & 15u) << 0;
        w |= (((uint32_t)a.y >> shift) & 15u) << 4;
        w |= (((uint32_t)a.z >> shift) & 15u) << 8;
        w |= (((uint32_t)a.w >> shift) & 15u) << 12;
        w |= (((uint32_t)b.x >> shift) & 15u) << 16;
        w |= (((uint32_t)b.y >> shift) & 15u) << 20;
        w |= (((uint32_t)b.z >> shift) & 15u) << 24;
        w |= (((uint32_t)b.w >> shift) & 15u) << 28;
        __builtin_nontemporal_store(w, key4 + t);
    } else {
        uint32_t w = 0;
        for (int j = 0; base + j < num_pins; ++j) {
            uint32_t k = (uint32_t)key[base + j];
            w |= ((k >> shift) & 15u) << (4 * j);
        }
        __builtin_nontemporal_store(w, key4 + t);
    }
}

__global__ void SortNode2Pin_coarse_kernel(const int* __restrict__ starts,
                                           const int* __restrict__ n2p,
                                           const int* __restrict__ key,
                                           const uint32_t* __restrict__ key4,
                                           int* __restrict__ out,
                                           int num_nodes) {
    int i = blockIdx.x * blockDim.x + threadIdx.x;
    if (i >= num_nodes) return;
    int s = starts[i];          // regular loads: coalesced + L1-reused
    int e = starts[i + 1];

    int mv = 16;                // running min nibble
    int bp = 0;                 // current best pin (0 if empty node)
    int bk = -1;                // exact key of bp, -1 = not fetched yet
    for (int j = s; j < e; ++j) {
        int p = n2p[j];                             // wave-contiguous, L1-hit
        uint32_t w = key4[(uint32_t)p >> 3];        // 4 MB table, L2-resident
        int n = (int)((w >> (((uint32_t)p & 7u) * 4u)) & 15u);
        if (n > mv) continue;
        if (n < mv) {
            mv = n; bp = p; bk = -1;                // new min: defer exact key
        } else {
            // tie on nibble: resolve with exact keys (rare, exec-masked)
            if (bk < 0) bk = key[bp];
            int k = key[p];
            if (k < bk) { bk = k; bp = p; }
        }
    }
    __builtin_nontemporal_store(bp, out + i);
}

// Fallback if workspace is too small for the coarse table.
__global__ void SortNode2Pin_direct_kernel(const int* __restrict__ starts,
                                           const int* __restrict__ n2p,
                                           const int* __restrict__ key,
                                           int* __restrict__ out,
                                           int num_nodes) {
    int i = blockIdx.x * blockDim.x + threadIdx.x;
    if (i >= num_nodes) return;
    int s = starts[i];
    int e = starts[i + 1];
    int best_pin = 0;
    int best_key = 0x7fffffff;
    for (int j = s; j < e; ++j) {
        int p = n2p[j];
        int k = key[p];
        if (k < best_key) { best_key = k; best_pin = p; }
    }
    out[i] = best_pin;
}

extern "C" void kernel_launch(void* const* d_in, const int* in_sizes, int n_in,
                              void* d_out, int out_size, void* d_ws, size_t ws_size,
                              hipStream_t stream) {
    const int* starts = (const int*)d_in[0];   // [num_nodes+1]
    const int* n2p    = (const int*)d_in[1];   // [num_pins]
    const int* key    = (const int*)d_in[2];   // [num_pins]
    int num_nodes = out_size;
    int num_pins  = in_sizes[1];

    size_t key4_words = (size_t)((num_pins + 7) / 8);
    size_t need = key4_words * sizeof(uint32_t);

    int block = 256;
    if (ws_size >= need) {
        int bits = 32 - __builtin_clz((unsigned)(num_pins - 1));  // ceil(log2)
        int shift = bits > 4 ? bits - 4 : 0;
        uint32_t* key4 = (uint32_t*)d_ws;

        int g1 = (int)((key4_words + block - 1) / block);
        build_key4_kernel<<<g1, block, 0, stream>>>(key, key4, num_pins, shift);

        int g2 = (num_nodes + block - 1) / block;
        SortNode2Pin_coarse_kernel<<<g2, block, 0, stream>>>(
            starts, n2p, key, key4, (int*)d_out, num_nodes);
    } else {
        int grid = (num_nodes + block - 1) / block;
        SortNode2Pin_direct_kernel<<<grid, block, 0, stream>>>(
            starts, n2p, key, (int*)d_out, num_nodes);
    }
}

// Round 5
// 86.756 us; speedup vs baseline: 2.4788x; 1.3789x over previous
//
#include <hip/hip_runtime.h>
#include <stdint.h>

// SortNode2Pin: per-node argmin over CSR pin slices by sorted_pin_map key.
// Cooperative-wave version: each wave processes the contiguous slot range of
// its 64 nodes (coalesced n2p), owner found by 6-step LDS binary search,
// per-node argmin via LDS atomics on a 4-bit coarse key (4 MB L2-resident
// table); exact keys fetched only for genuinely tied nodes, from per-lane
// register-buffered slots (no re-loops).

typedef int iv4 __attribute__((ext_vector_type(4)));

#define NPB 256   // nodes per block
#define SBUF 8    // register-buffered slots per lane (range/64 > 8 is ~8-sigma)

__global__ void build_key4_kernel(const int* __restrict__ key,
                                  uint32_t* __restrict__ key4,
                                  int num_pins, int shift) {
    int t = blockIdx.x * blockDim.x + threadIdx.x;
    int base = t * 8;
    if (base >= num_pins) return;
    if (base + 8 <= num_pins) {
        const iv4* kp = (const iv4*)(key + base);
        iv4 a = __builtin_nontemporal_load(kp);
        iv4 b = __builtin_nontemporal_load(kp + 1);
        uint32_t w = 0;
        w |= (((uint32_t)a.x >> shift) & 15u) << 0;
        w |= (((uint32_t)a.y >> shift) & 15u) << 4;
        w |= (((uint32_t)a.z >> shift) & 15u) << 8;
        w |= (((uint32_t)a.w >> shift) & 15u) << 12;
        w |= (((uint32_t)b.x >> shift) & 15u) << 16;
        w |= (((uint32_t)b.y >> shift) & 15u) << 20;
        w |= (((uint32_t)b.z >> shift) & 15u) << 24;
        w |= (((uint32_t)b.w >> shift) & 15u) << 28;
        __builtin_nontemporal_store(w, key4 + t);
    } else {
        uint32_t w = 0;
        for (int j = 0; base + j < num_pins; ++j) {
            uint32_t k = (uint32_t)key[base + j];
            w |= ((k >> shift) & 15u) << (4 * j);
        }
        __builtin_nontemporal_store(w, key4 + t);
    }
}

__global__ __launch_bounds__(256) void SortNode2Pin_coop_kernel(
        const int* __restrict__ starts,
        const int* __restrict__ n2p,
        const int* __restrict__ key,
        const uint32_t* __restrict__ key4,
        int* __restrict__ out,
        int num_nodes) {
    __shared__ int B[NPB + 1];                  // segment boundaries
    __shared__ uint32_t win32[NPB];             // min (nib<<23 | pin)
    __shared__ uint32_t cnt[NPB];               // #slots attaining min nib
    __shared__ unsigned long long res64[NPB];   // min (key<<23 | pin), ties only

    int t = threadIdx.x;
    int i0 = blockIdx.x * NPB;

    {
        int idx = i0 + t; if (idx > num_nodes) idx = num_nodes;
        B[t] = starts[idx];
        if (t == 0) {
            int idx2 = i0 + NPB; if (idx2 > num_nodes) idx2 = num_nodes;
            B[NPB] = starts[idx2];
        }
        win32[t] = 0xFFFFFFFFu;
        cnt[t] = 0u;
        res64[t] = ~0ull;
    }
    __syncthreads();

    int w = t >> 6;
    int lane = t & 63;
    int wbase = w * 64;                 // block-local node base of this wave
    int jbeg = B[wbase];
    int jend = B[wbase + 64];

    uint32_t segpin[SBUF];              // (seg8<<23)|pin23  (fits u32)
    uint32_t cpack = 0;                 // 8 nibbles packed
    int nbuf = 0;

    for (int j = jbeg + lane; j < jend; j += 64) {
        int p = __builtin_nontemporal_load(n2p + j);     // coalesced stream
        uint32_t wk = key4[(uint32_t)p >> 3];            // L2-resident gather
        uint32_t nib = (wk >> (((uint32_t)p & 7u) * 4u)) & 15u;
        int k = wbase;                                   // owner: binary search
        #pragma unroll
        for (int st = 32; st >= 1; st >>= 1)
            if (B[k + st] <= j) k += st;
        atomicMin(&win32[k], (nib << 23) | (uint32_t)p);
        if (nbuf < SBUF) {
            segpin[nbuf] = ((uint32_t)k << 23) | (uint32_t)p;
            cpack |= nib << (4 * nbuf);
            ++nbuf;
        } else {
            // overflow (practically never): resolve exactly, force exact path
            int ek = key[p];
            atomicMin(&res64[k],
                      ((unsigned long long)(uint32_t)ek << 23) | (unsigned long long)(uint32_t)p);
            atomicAdd(&cnt[k], 2u);
        }
    }
    __syncthreads();

    // pass 2a: count slots attaining each node's min nibble
    for (int b = 0; b < nbuf; ++b) {
        uint32_t sp = segpin[b];
        int k = (int)(sp >> 23);
        uint32_t nib = (cpack >> (4 * b)) & 15u;
        if (nib == (win32[k] >> 23)) atomicAdd(&cnt[k], 1u);
    }
    __syncthreads();

    // pass 2b: exact resolution for tied nodes only (masked, buffered slots)
    for (int b = 0; b < nbuf; ++b) {
        uint32_t sp = segpin[b];
        int k = (int)(sp >> 23);
        uint32_t p = sp & 0x7FFFFFu;
        uint32_t nib = (cpack >> (4 * b)) & 15u;
        if (nib == (win32[k] >> 23) && cnt[k] > 1u) {
            int ek = key[(int)p];
            atomicMin(&res64[k],
                      ((unsigned long long)(uint32_t)ek << 23) | (unsigned long long)p);
        }
    }
    __syncthreads();

    int node = i0 + t;
    if (node < num_nodes) {
        int r;
        if (B[t] == B[t + 1])      r = 0;                           // empty
        else if (cnt[t] > 1u)      r = (int)(res64[t] & 0x7FFFFFull);
        else                       r = (int)(win32[t] & 0x7FFFFFu);
        __builtin_nontemporal_store(r, out + node);
    }
}

// Fallback if workspace is too small for the coarse table.
__global__ void SortNode2Pin_direct_kernel(const int* __restrict__ starts,
                                           const int* __restrict__ n2p,
                                           const int* __restrict__ key,
                                           int* __restrict__ out,
                                           int num_nodes) {
    int i = blockIdx.x * blockDim.x + threadIdx.x;
    if (i >= num_nodes) return;
    int s = starts[i];
    int e = starts[i + 1];
    int best_pin = 0;
    int best_key = 0x7fffffff;
    for (int j = s; j < e; ++j) {
        int p = n2p[j];
        int k = key[p];
        if (k < best_key) { best_key = k; best_pin = p; }
    }
    out[i] = best_pin;
}

extern "C" void kernel_launch(void* const* d_in, const int* in_sizes, int n_in,
                              void* d_out, int out_size, void* d_ws, size_t ws_size,
                              hipStream_t stream) {
    const int* starts = (const int*)d_in[0];   // [num_nodes+1]
    const int* n2p    = (const int*)d_in[1];   // [num_pins]
    const int* key    = (const int*)d_in[2];   // [num_pins]
    int num_nodes = out_size;
    int num_pins  = in_sizes[1];

    size_t key4_words = (size_t)((num_pins + 7) / 8);
    size_t need = key4_words * sizeof(uint32_t);

    int block = 256;
    if (ws_size >= need) {
        int bits = 32 - __builtin_clz((unsigned)(num_pins - 1));  // ceil(log2)
        int shift = bits > 4 ? bits - 4 : 0;
        uint32_t* key4 = (uint32_t*)d_ws;

        int g1 = (int)((key4_words + block - 1) / block);
        build_key4_kernel<<<g1, block, 0, stream>>>(key, key4, num_pins, shift);

        int g2 = (num_nodes + NPB - 1) / NPB;
        SortNode2Pin_coop_kernel<<<g2, block, 0, stream>>>(
            starts, n2p, key, key4, (int*)d_out, num_nodes);
    } else {
        int grid = (num_nodes + block - 1) / block;
        SortNode2Pin_direct_kernel<<<grid, block, 0, stream>>>(
            starts, n2p, key, (int*)d_out, num_nodes);
    }
}